// Round 1
// baseline (676.385 us; speedup 1.0000x reference)
//
#include <hip/hip_runtime.h>

#define NN 131072
#define EE 524288

typedef short bf16x8 __attribute__((ext_vector_type(8)));
typedef float f32x4 __attribute__((ext_vector_type(4)));

__device__ __forceinline__ unsigned short f2bf(float f) {
  unsigned u = __float_as_uint(f);
  u += 0x7fffu + ((u >> 16) & 1u);   // RNE
  return (unsigned short)(u >> 16);
}
__device__ __forceinline__ float bflo(unsigned u) { return __uint_as_float(u << 16); }
__device__ __forceinline__ float bfhi(unsigned u) { return __uint_as_float(u & 0xffff0000u); }

// ---------------- CSR build ----------------
__global__ __launch_bounds__(256) void khist(const int* __restrict__ q0, const int* __restrict__ q1,
                                             const int* __restrict__ q2, const int* __restrict__ q3,
                                             unsigned* __restrict__ counts) {
  unsigned e = blockIdx.x * 256u + threadIdx.x;          // 0..4E-1
  unsigned t = e >> 19, i = e & (EE - 1u);
  const int* dd = (t == 0) ? q0 : (t == 1) ? q1 : (t == 2) ? q2 : q3;
  atomicAdd(&counts[t * NN + (unsigned)dd[i]], 1u);
}

__global__ __launch_bounds__(256) void kscan1(const uint4* __restrict__ c4, unsigned* __restrict__ rp,
                                              unsigned* __restrict__ bsums) {
  __shared__ unsigned sh[256];
  int tid = threadIdx.x;
  uint4 c = c4[blockIdx.x * 256 + tid];
  unsigned tsum = c.x + c.y + c.z + c.w;
  sh[tid] = tsum;
  __syncthreads();
  for (int o = 1; o < 256; o <<= 1) {
    unsigned v = (tid >= o) ? sh[tid - o] : 0u;
    __syncthreads();
    sh[tid] += v;
    __syncthreads();
  }
  unsigned excl = sh[tid] - tsum;
  uint4 w; w.x = excl; w.y = excl + c.x; w.z = w.y + c.y; w.w = w.z + c.z;
  reinterpret_cast<uint4*>(rp)[blockIdx.x * 256 + tid] = w;
  if (tid == 255) bsums[blockIdx.x] = sh[255];
}

__global__ __launch_bounds__(512) void kscan2(const unsigned* __restrict__ bsums, unsigned* __restrict__ bso) {
  __shared__ unsigned sh[512];
  int tid = threadIdx.x;
  unsigned x = bsums[tid];
  sh[tid] = x;
  __syncthreads();
  for (int o = 1; o < 512; o <<= 1) {
    unsigned v = (tid >= o) ? sh[tid - o] : 0u;
    __syncthreads();
    sh[tid] += v;
    __syncthreads();
  }
  bso[tid] = sh[tid] - x;
}

__global__ __launch_bounds__(256) void kscan3(unsigned* __restrict__ rp, const unsigned* __restrict__ bso,
                                              unsigned* __restrict__ cursor) {
  unsigned i = blockIdx.x * 256u + threadIdx.x;          // 0..4N-1
  unsigned v = rp[i] + bso[i >> 10];
  rp[i] = v;
  cursor[i] = v;
  if (i == 0) rp[4u * NN] = 4u * EE;
}

__global__ __launch_bounds__(256) void kfill(const int* __restrict__ s0, const int* __restrict__ s1,
                                             const int* __restrict__ s2, const int* __restrict__ s3,
                                             const float* __restrict__ w0, const float* __restrict__ w1,
                                             const float* __restrict__ w2, const float* __restrict__ w3,
                                             unsigned* __restrict__ cursor, uint2* __restrict__ edges) {
  unsigned e = blockIdx.x * 256u + threadIdx.x;
  unsigned t = e >> 19, i = e & (EE - 1u);
  const int* ss = (t == 0) ? s0 : (t == 1) ? s1 : (t == 2) ? s2 : s3;
  const float* ww = (t == 0) ? w0 : (t == 1) ? w1 : (t == 2) ? w2 : w3;
  unsigned src = (unsigned)ss[i];
  unsigned dst = (unsigned)ss[i + EE];
  float w = ww[i];
  unsigned pos = atomicAdd(&cursor[t * NN + dst], 1u);
  edges[pos] = make_uint2(src, __float_as_uint(w));
}

// ---------------- fp32 -> bf16 cast ----------------
__global__ __launch_bounds__(256) void kcast(const float4* __restrict__ x, ushort4* __restrict__ o) {
  unsigned i = blockIdx.x * 256u + threadIdx.x;
  float4 v = x[i];
  ushort4 r;
  r.x = f2bf(v.x); r.y = f2bf(v.y); r.z = f2bf(v.z); r.w = f2bf(v.w);
  o[i] = r;
}

// ---------------- aggregate (pull): Z[d][t*128+c] = sum_{e in CSR_t(d)} ew*X[src][c] ----------------
__global__ __launch_bounds__(256) void kagg(const uint2* __restrict__ edges, const unsigned* __restrict__ rp,
                                            const unsigned short* __restrict__ X, unsigned short* __restrict__ Z) {
  int lane = threadIdx.x & 63;
  unsigned d = (blockIdx.x << 2) + (threadIdx.x >> 6);
  size_t zoff = (size_t)d * 512 + (unsigned)(lane * 2);
#pragma unroll
  for (int t = 0; t < 4; ++t) {
    float ax = 0.f, ay = 0.f;
    unsigned s = rp[t * NN + d], e = rp[t * NN + d + 1];
    unsigned j = s;
    for (; j + 1 < e; j += 2) {
      uint2 e0 = edges[j], e1 = edges[j + 1];
      unsigned u0 = *reinterpret_cast<const unsigned*>(X + (size_t)e0.x * 128 + lane * 2);
      unsigned u1 = *reinterpret_cast<const unsigned*>(X + (size_t)e1.x * 128 + lane * 2);
      float w0 = __uint_as_float(e0.y), w1 = __uint_as_float(e1.y);
      ax = fmaf(w0, bflo(u0), ax); ay = fmaf(w0, bfhi(u0), ay);
      ax = fmaf(w1, bflo(u1), ax); ay = fmaf(w1, bfhi(u1), ay);
    }
    if (j < e) {
      uint2 ed = edges[j];
      unsigned u = *reinterpret_cast<const unsigned*>(X + (size_t)ed.x * 128 + lane * 2);
      float w = __uint_as_float(ed.y);
      ax = fmaf(w, bflo(u), ax); ay = fmaf(w, bfhi(u), ay);
    }
    unsigned o = ((unsigned)f2bf(ay) << 16) | (unsigned)f2bf(ax);
    *reinterpret_cast<unsigned*>(Z + zoff + t * 128) = o;
  }
}

// ---------------- GEMM [N,512]x[512,128] (bf16 MFMA) + bias + LayerNorm fused ----------------
__global__ __launch_bounds__(256) void gemm_ln(
    const unsigned short* __restrict__ Z,
    const float* __restrict__ Wa, const float* __restrict__ Wb,
    const float* __restrict__ Wc, const float* __restrict__ Wd,
    const float* __restrict__ ba, const float* __restrict__ bb_,
    const float* __restrict__ bc, const float* __restrict__ bd,
    const float* __restrict__ gw, const float* __restrict__ bw,
    unsigned short* __restrict__ outb, float* __restrict__ outf, int wf32) {
  __shared__ unsigned short sA[128 * 128];
  __shared__ unsigned short sW[128 * 128];
  const int tid = threadIdx.x;
  const int lane = tid & 63;
  const int wv = tid >> 6;
  const int rlo = lane & 15;
  const int khi = lane >> 4;
  const size_t tiler = blockIdx.x;

  f32x4 acc[2][8];
#pragma unroll
  for (int m = 0; m < 2; ++m)
#pragma unroll
    for (int n = 0; n < 8; ++n) acc[m][n] = (f32x4){0.f, 0.f, 0.f, 0.f};

  const float* Ws[4] = {Wa, Wb, Wc, Wd};
  for (int t = 0; t < 4; ++t) {
    __syncthreads();
    {  // stage W_t transposed + swizzled: sW row c holds W[k][c] at byte (2k)^((c&7)<<4)
      const float* W = Ws[t];
      int c = tid & 127;
      int kh = tid >> 7;
      for (int k = kh; k < 128; k += 2) {
        unsigned short b = f2bf(W[k * 128 + c]);
        *(unsigned short*)((char*)sW + c * 256 + ((2 * k) ^ ((c & 7) << 4))) = b;
      }
    }
    {  // stage A chunk: rows tiler*128.., k-slice t*128..t*128+127 of Z
#pragma unroll
      for (int it = 0; it < 8; ++it) {
        int idx = it * 256 + tid;
        int row = idx >> 4, ch = idx & 15;
        const uint4* src = reinterpret_cast<const uint4*>(Z + ((tiler * 128 + row) * 512 + t * 128));
        uint4 v = src[ch];
        *(uint4*)((char*)sA + row * 256 + ((ch * 16) ^ ((row & 7) << 4))) = v;
      }
    }
    __syncthreads();
#pragma unroll
    for (int q = 0; q < 4; ++q) {
      int ko = q * 64 + khi * 16;  // byte offset of this lane's 8 contiguous k
      int r0 = wv * 32 + rlo;
      bf16x8 a0 = *(const bf16x8*)((const char*)sA + r0 * 256 + (ko ^ ((r0 & 7) << 4)));
      int r1 = r0 + 16;
      bf16x8 a1 = *(const bf16x8*)((const char*)sA + r1 * 256 + (ko ^ ((r1 & 7) << 4)));
#pragma unroll
      for (int n = 0; n < 8; ++n) {
        int cc = n * 16 + rlo;
        bf16x8 bfr = *(const bf16x8*)((const char*)sW + cc * 256 + (ko ^ ((cc & 7) << 4)));
        acc[0][n] = __builtin_amdgcn_mfma_f32_16x16x32_bf16(a0, bfr, acc[0][n], 0, 0, 0);
        acc[1][n] = __builtin_amdgcn_mfma_f32_16x16x32_bf16(a1, bfr, acc[1][n], 0, 0, 0);
      }
    }
  }
  // epilogue: bias sum + LayerNorm per row (rows live across 16-lane groups)
  float bsum[8], gg[8], bwv[8];
#pragma unroll
  for (int n = 0; n < 8; ++n) {
    int c = n * 16 + rlo;
    bsum[n] = ba[c] + bb_[c] + bc[c] + bd[c];
    gg[n] = gw[c];
    bwv[n] = bw[c];
  }
#pragma unroll
  for (int m = 0; m < 2; ++m) {
#pragma unroll
    for (int rg = 0; rg < 4; ++rg) {
      float v[8];
      float s = 0.f;
#pragma unroll
      for (int n = 0; n < 8; ++n) {
        v[n] = acc[m][n][rg] + bsum[n];
        s += v[n];
      }
      s += __shfl_xor(s, 1, 64);
      s += __shfl_xor(s, 2, 64);
      s += __shfl_xor(s, 4, 64);
      s += __shfl_xor(s, 8, 64);
      float mu = s * (1.f / 128.f);
      float ss = 0.f;
#pragma unroll
      for (int n = 0; n < 8; ++n) {
        v[n] -= mu;
        ss += v[n] * v[n];
      }
      ss += __shfl_xor(ss, 1, 64);
      ss += __shfl_xor(ss, 2, 64);
      ss += __shfl_xor(ss, 4, 64);
      ss += __shfl_xor(ss, 8, 64);
      float inv = rsqrtf(ss * (1.f / 128.f) + 1e-5f);
      size_t r = tiler * 128 + wv * 32 + m * 16 + khi * 4 + rg;
      if (wf32) {
#pragma unroll
        for (int n = 0; n < 8; ++n) outf[r * 128 + n * 16 + rlo] = v[n] * inv * gg[n] + bwv[n];
      } else {
#pragma unroll
        for (int n = 0; n < 8; ++n) outb[r * 128 + n * 16 + rlo] = f2bf(v[n] * inv * gg[n] + bwv[n]);
      }
    }
  }
}

extern "C" void kernel_launch(void* const* d_in, const int* in_sizes, int n_in,
                              void* d_out, int out_size, void* d_ws, size_t ws_size,
                              hipStream_t stream) {
  (void)n_in; (void)out_size; (void)ws_size;
  const float* x = (const float*)d_in[0];
  const int* ei[4];
  const float *ew[4], *W1[4], *b1[4], *W2[4], *b2[4];
  const float *g1, *be1, *g2, *be2;
  if (in_sizes[2] == EE) {  // setup_inputs dict order (interleaved per type)
    for (int t = 0; t < 4; ++t) {
      int base = 1 + t * 6;
      ei[t] = (const int*)d_in[base + 0];
      ew[t] = (const float*)d_in[base + 1];
      W1[t] = (const float*)d_in[base + 2];
      b1[t] = (const float*)d_in[base + 3];
      W2[t] = (const float*)d_in[base + 4];
      b2[t] = (const float*)d_in[base + 5];
    }
  } else {  // reference() argument order
    for (int t = 0; t < 4; ++t) {
      ei[t] = (const int*)d_in[1 + t];
      ew[t] = (const float*)d_in[5 + t];
      W1[t] = (const float*)d_in[9 + t * 4 + 0];
      b1[t] = (const float*)d_in[9 + t * 4 + 1];
      W2[t] = (const float*)d_in[9 + t * 4 + 2];
      b2[t] = (const float*)d_in[9 + t * 4 + 3];
    }
  }
  g1 = (const float*)d_in[25];
  be1 = (const float*)d_in[26];
  g2 = (const float*)d_in[27];
  be2 = (const float*)d_in[28];

  char* ws = (char*)d_ws;
  size_t off = 0;
  auto take = [&](size_t b) { char* p = ws + off; off = (off + b + 255) & ~(size_t)255; return p; };
  unsigned* counts = (unsigned*)take(4ull * NN * 4);
  unsigned* rp     = (unsigned*)take((4ull * NN + 1) * 4);
  unsigned* cursor = (unsigned*)take(4ull * NN * 4);
  unsigned* bsums  = (unsigned*)take(512 * 4);
  unsigned* bso    = (unsigned*)take(512 * 4);
  uint2* edges     = (uint2*)take(4ull * EE * 8);
  unsigned short* Xb = (unsigned short*)take((size_t)NN * 128 * 2);
  unsigned short* Z  = (unsigned short*)take((size_t)NN * 512 * 2);

  hipMemsetAsync(counts, 0, 4ull * NN * 4, stream);
  khist<<<4 * EE / 256, 256, 0, stream>>>(ei[0] + EE, ei[1] + EE, ei[2] + EE, ei[3] + EE, counts);
  kscan1<<<512, 256, 0, stream>>>((const uint4*)counts, rp, bsums);
  kscan2<<<1, 512, 0, stream>>>(bsums, bso);
  kscan3<<<4 * NN / 256, 256, 0, stream>>>(rp, bso, cursor);
  kfill<<<4 * EE / 256, 256, 0, stream>>>(ei[0], ei[1], ei[2], ei[3], ew[0], ew[1], ew[2], ew[3], cursor, edges);
  kcast<<<NN * 128 / 4 / 256, 256, 0, stream>>>((const float4*)x, (ushort4*)Xb);

  // layer 1: aggregate X -> Z, GEMM+LN -> Yb (bf16, stored in d_out as scratch)
  kagg<<<NN / 4, 256, 0, stream>>>(edges, rp, Xb, Z);
  unsigned short* Yb = (unsigned short*)d_out;
  gemm_ln<<<NN / 128, 256, 0, stream>>>(Z, W1[0], W1[1], W1[2], W1[3],
                                        b1[0], b1[1], b1[2], b1[3], g1, be1, Yb, nullptr, 0);
  // layer 2: aggregate Yb -> Z, GEMM+LN -> d_out (fp32)
  kagg<<<NN / 4, 256, 0, stream>>>(edges, rp, Yb, Z);
  gemm_ln<<<NN / 128, 256, 0, stream>>>(Z, W2[0], W2[1], W2[2], W2[3],
                                        b2[0], b2[1], b2[2], b2[3], g2, be2, nullptr, (float*)d_out, 1);
}

// Round 2
// 503.710 us; speedup vs baseline: 1.3428x; 1.3428x over previous
//
#include <hip/hip_runtime.h>

#define NN 131072
#define EE 524288

typedef short bf16x8 __attribute__((ext_vector_type(8)));
typedef float f32x4 __attribute__((ext_vector_type(4)));

__device__ __forceinline__ unsigned short f2bf(float f) {
  unsigned u = __float_as_uint(f);
  u += 0x7fffu + ((u >> 16) & 1u);   // RNE
  return (unsigned short)(u >> 16);
}
__device__ __forceinline__ float bflo(unsigned u) { return __uint_as_float(u << 16); }
__device__ __forceinline__ float bfhi(unsigned u) { return __uint_as_float(u & 0xffff0000u); }

// ---------------- coarse histogram over dst>>8 (512 buckets) ----------------
__global__ __launch_bounds__(256) void khc(const int* __restrict__ d0, const int* __restrict__ d1,
                                           const int* __restrict__ d2, const int* __restrict__ d3,
                                           unsigned* __restrict__ gc) {
  __shared__ unsigned h[512];
  for (int i = threadIdx.x; i < 512; i += 256) h[i] = 0;
  __syncthreads();
  unsigned base = blockIdx.x * 2048u + threadIdx.x;
#pragma unroll
  for (int k = 0; k < 8; ++k) {
    unsigned e = base + k * 256u;
    unsigned t = e >> 19, i = e & (EE - 1u);
    const int* dd = (t == 0) ? d0 : (t == 1) ? d1 : (t == 2) ? d2 : d3;
    atomicAdd(&h[((unsigned)dd[i]) >> 8], 1u);
  }
  __syncthreads();
  for (int i = threadIdx.x; i < 512; i += 256) atomicAdd(&gc[i], h[i]);
}

// ---------------- scan 512 coarse counts -> rpc[513], cursor init ----------------
__global__ __launch_bounds__(512) void kscan_small(const unsigned* __restrict__ gc, unsigned* __restrict__ rpc,
                                                   unsigned* __restrict__ cursor, unsigned* __restrict__ rp_fine) {
  __shared__ unsigned sh[512];
  int tid = threadIdx.x;
  unsigned x = gc[tid];
  sh[tid] = x;
  __syncthreads();
  for (int o = 1; o < 512; o <<= 1) {
    unsigned v = (tid >= o) ? sh[tid - o] : 0u;
    __syncthreads();
    sh[tid] += v;
    __syncthreads();
  }
  unsigned excl = sh[tid] - x;
  rpc[tid] = excl;
  cursor[tid] = excl;
  if (tid == 511) rpc[512] = sh[511];
  if (tid == 0) rp_fine[4u * NN] = 4u * EE;
}

// ---------------- phase A: bin edges into 512 coarse buckets ----------------
// record: word0 = src | (lowkey<<17), word1 = bits(w); lowkey = (dst&255)*4 + t
__global__ __launch_bounds__(256) void kbinA(
    const int* __restrict__ e0, const int* __restrict__ e1, const int* __restrict__ e2, const int* __restrict__ e3,
    const float* __restrict__ w0, const float* __restrict__ w1, const float* __restrict__ w2, const float* __restrict__ w3,
    unsigned* __restrict__ cursor, uint2* __restrict__ tmp) {
  __shared__ unsigned hist[512];
  __shared__ unsigned base[512];
  int tid = threadIdx.x;
  unsigned t = blockIdx.x >> 7;          // 128 chunks per type
  unsigned chunk = blockIdx.x & 127u;
  const int* ei = (t == 0) ? e0 : (t == 1) ? e1 : (t == 2) ? e2 : e3;
  const float* ew = (t == 0) ? w0 : (t == 1) ? w1 : (t == 2) ? w2 : w3;
  const int* srcp = ei;
  const int* dstp = ei + EE;
  unsigned ib = chunk * 4096u;
  for (int i = tid; i < 512; i += 256) hist[i] = 0;
  __syncthreads();
  unsigned km[16], sm[16];
  float wm[16];
#pragma unroll
  for (int k = 0; k < 16; ++k) {
    unsigned i = ib + k * 256u + tid;
    unsigned dst = (unsigned)dstp[i];
    sm[k] = (unsigned)srcp[i];
    wm[k] = ew[i];
    km[k] = (dst << 2) | t;              // key = dst*4+t; bucket = key>>10
    atomicAdd(&hist[dst >> 8], 1u);
  }
  __syncthreads();
  for (int j = tid; j < 512; j += 256) {
    unsigned c = hist[j];
    base[j] = c ? atomicAdd(&cursor[j], c) : 0u;
    hist[j] = 0u;                        // reuse as local cursor
  }
  __syncthreads();
#pragma unroll
  for (int k = 0; k < 16; ++k) {
    unsigned b = km[k] >> 10;
    unsigned l = atomicAdd(&hist[b], 1u);
    tmp[(size_t)base[b] + l] = make_uint2(sm[k] | ((km[k] & 1023u) << 17), __float_as_uint(wm[k]));
  }
}

// ---------------- phase B: per-bucket counting sort over 1024 fine keys ----------------
__global__ __launch_bounds__(256) void kbinB(const unsigned* __restrict__ rpc, const uint2* __restrict__ tmp,
                                             unsigned* __restrict__ rp_fine, uint2* __restrict__ edges) {
  __shared__ unsigned cnts[1024];
  __shared__ unsigned ps[256];
  int tid = threadIdx.x;
  unsigned b = blockIdx.x;
  unsigned s = rpc[b], e = rpc[b + 1];
  unsigned cnt = e - s;
  for (int j = tid; j < 1024; j += 256) cnts[j] = 0;
  __syncthreads();
  for (unsigned i = tid; i < cnt; i += 256) {
    unsigned lk = tmp[s + i].x >> 17;
    atomicAdd(&cnts[lk], 1u);
  }
  __syncthreads();
  unsigned c4[4], lsum = 0;
#pragma unroll
  for (int q = 0; q < 4; ++q) { c4[q] = cnts[tid * 4 + q]; lsum += c4[q]; }
  ps[tid] = lsum;
  __syncthreads();
  for (int o = 1; o < 256; o <<= 1) {
    unsigned v = (tid >= o) ? ps[tid - o] : 0u;
    __syncthreads();
    ps[tid] += v;
    __syncthreads();
  }
  unsigned excl = ps[tid] - lsum;
  __syncthreads();
#pragma unroll
  for (int q = 0; q < 4; ++q) {
    rp_fine[b * 1024u + (unsigned)tid * 4u + q] = s + excl;
    cnts[tid * 4 + q] = excl;            // lcur init
    excl += c4[q];
  }
  __syncthreads();
  for (unsigned i = tid; i < cnt; i += 256) {
    uint2 r = tmp[s + i];
    unsigned lk = r.x >> 17;
    unsigned p = atomicAdd(&cnts[lk], 1u);
    edges[(size_t)s + p] = make_uint2(r.x & 0x1ffffu, r.y);
  }
}

// ---------------- fp32 -> bf16 cast ----------------
__global__ __launch_bounds__(256) void kcast(const float4* __restrict__ x, ushort4* __restrict__ o) {
  unsigned i = blockIdx.x * 256u + threadIdx.x;
  float4 v = x[i];
  ushort4 r;
  r.x = f2bf(v.x); r.y = f2bf(v.y); r.z = f2bf(v.z); r.w = f2bf(v.w);
  o[i] = r;
}

// ---------------- aggregate (pull): Z[d][t*128+c] = sum ew*X[src][c] ----------------
// rp keyed by dst*4+t: one wave per dst reads one contiguous edge run.
__global__ __launch_bounds__(256) void kagg(const uint2* __restrict__ edges, const unsigned* __restrict__ rp,
                                            const unsigned short* __restrict__ X, unsigned short* __restrict__ Z) {
  int lane = threadIdx.x & 63;
  unsigned d = (blockIdx.x << 2) + (threadIdx.x >> 6);
  unsigned xo = (unsigned)(lane * 2);
  size_t zoff = (size_t)d * 512 + xo;
  unsigned sb[5];
#pragma unroll
  for (int q = 0; q < 5; ++q) sb[q] = rp[d * 4u + q];
#pragma unroll
  for (int t = 0; t < 4; ++t) {
    unsigned s = sb[t], e = sb[t + 1];
    float ax = 0.f, ay = 0.f;
    unsigned j = s;
    for (; j + 4 <= e; j += 4) {
      uint2 q0 = edges[j], q1 = edges[j + 1], q2 = edges[j + 2], q3 = edges[j + 3];
      unsigned u0 = *(const unsigned*)(X + (size_t)q0.x * 128 + xo);
      unsigned u1 = *(const unsigned*)(X + (size_t)q1.x * 128 + xo);
      unsigned u2 = *(const unsigned*)(X + (size_t)q2.x * 128 + xo);
      unsigned u3 = *(const unsigned*)(X + (size_t)q3.x * 128 + xo);
      float w0 = __uint_as_float(q0.y), w1 = __uint_as_float(q1.y);
      float w2 = __uint_as_float(q2.y), w3 = __uint_as_float(q3.y);
      ax = fmaf(w0, bflo(u0), ax); ay = fmaf(w0, bfhi(u0), ay);
      ax = fmaf(w1, bflo(u1), ax); ay = fmaf(w1, bfhi(u1), ay);
      ax = fmaf(w2, bflo(u2), ax); ay = fmaf(w2, bfhi(u2), ay);
      ax = fmaf(w3, bflo(u3), ax); ay = fmaf(w3, bfhi(u3), ay);
    }
    for (; j < e; ++j) {
      uint2 q0 = edges[j];
      unsigned u0 = *(const unsigned*)(X + (size_t)q0.x * 128 + xo);
      float w0 = __uint_as_float(q0.y);
      ax = fmaf(w0, bflo(u0), ax); ay = fmaf(w0, bfhi(u0), ay);
    }
    *(unsigned*)(Z + zoff + t * 128) = ((unsigned)f2bf(ay) << 16) | (unsigned)f2bf(ax);
  }
}

// ---------------- GEMM [N,512]x[512,128] (bf16 MFMA) + bias + LayerNorm fused ----------------
__global__ __launch_bounds__(256) void gemm_ln(
    const unsigned short* __restrict__ Z,
    const float* __restrict__ Wa, const float* __restrict__ Wb,
    const float* __restrict__ Wc, const float* __restrict__ Wd,
    const float* __restrict__ ba, const float* __restrict__ bb_,
    const float* __restrict__ bc, const float* __restrict__ bd,
    const float* __restrict__ gw, const float* __restrict__ bw,
    unsigned short* __restrict__ outb, float* __restrict__ outf, int wf32) {
  __shared__ unsigned short sA[128 * 128];
  __shared__ unsigned short sW[128 * 128];
  const int tid = threadIdx.x;
  const int lane = tid & 63;
  const int wv = tid >> 6;
  const int rlo = lane & 15;
  const int khi = lane >> 4;
  const size_t tiler = blockIdx.x;

  f32x4 acc[2][8];
#pragma unroll
  for (int m = 0; m < 2; ++m)
#pragma unroll
    for (int n = 0; n < 8; ++n) acc[m][n] = (f32x4){0.f, 0.f, 0.f, 0.f};

  const float* Ws[4] = {Wa, Wb, Wc, Wd};
  for (int t = 0; t < 4; ++t) {
    __syncthreads();
    {  // stage W_t transposed + swizzled
      const float* W = Ws[t];
      int c = tid & 127;
      int kh = tid >> 7;
      for (int k = kh; k < 128; k += 2) {
        unsigned short b = f2bf(W[k * 128 + c]);
        *(unsigned short*)((char*)sW + c * 256 + ((2 * k) ^ ((c & 7) << 4))) = b;
      }
    }
    {  // stage A chunk
#pragma unroll
      for (int it = 0; it < 8; ++it) {
        int idx = it * 256 + tid;
        int row = idx >> 4, ch = idx & 15;
        const uint4* src = reinterpret_cast<const uint4*>(Z + ((tiler * 128 + row) * 512 + t * 128));
        uint4 v = src[ch];
        *(uint4*)((char*)sA + row * 256 + ((ch * 16) ^ ((row & 7) << 4))) = v;
      }
    }
    __syncthreads();
#pragma unroll
    for (int q = 0; q < 4; ++q) {
      int ko = q * 64 + khi * 16;
      int r0 = wv * 32 + rlo;
      bf16x8 a0 = *(const bf16x8*)((const char*)sA + r0 * 256 + (ko ^ ((r0 & 7) << 4)));
      int r1 = r0 + 16;
      bf16x8 a1 = *(const bf16x8*)((const char*)sA + r1 * 256 + (ko ^ ((r1 & 7) << 4)));
#pragma unroll
      for (int n = 0; n < 8; ++n) {
        int cc = n * 16 + rlo;
        bf16x8 bfr = *(const bf16x8*)((const char*)sW + cc * 256 + (ko ^ ((cc & 7) << 4)));
        acc[0][n] = __builtin_amdgcn_mfma_f32_16x16x32_bf16(a0, bfr, acc[0][n], 0, 0, 0);
        acc[1][n] = __builtin_amdgcn_mfma_f32_16x16x32_bf16(a1, bfr, acc[1][n], 0, 0, 0);
      }
    }
  }
  float bsum[8], gg[8], bwv[8];
#pragma unroll
  for (int n = 0; n < 8; ++n) {
    int c = n * 16 + rlo;
    bsum[n] = ba[c] + bb_[c] + bc[c] + bd[c];
    gg[n] = gw[c];
    bwv[n] = bw[c];
  }
#pragma unroll
  for (int m = 0; m < 2; ++m) {
#pragma unroll
    for (int rg = 0; rg < 4; ++rg) {
      float v[8];
      float s = 0.f;
#pragma unroll
      for (int n = 0; n < 8; ++n) {
        v[n] = acc[m][n][rg] + bsum[n];
        s += v[n];
      }
      s += __shfl_xor(s, 1, 64);
      s += __shfl_xor(s, 2, 64);
      s += __shfl_xor(s, 4, 64);
      s += __shfl_xor(s, 8, 64);
      float mu = s * (1.f / 128.f);
      float ss = 0.f;
#pragma unroll
      for (int n = 0; n < 8; ++n) {
        v[n] -= mu;
        ss += v[n] * v[n];
      }
      ss += __shfl_xor(ss, 1, 64);
      ss += __shfl_xor(ss, 2, 64);
      ss += __shfl_xor(ss, 4, 64);
      ss += __shfl_xor(ss, 8, 64);
      float inv = rsqrtf(ss * (1.f / 128.f) + 1e-5f);
      size_t r = tiler * 128 + wv * 32 + m * 16 + khi * 4 + rg;
      if (wf32) {
#pragma unroll
        for (int n = 0; n < 8; ++n) outf[r * 128 + n * 16 + rlo] = v[n] * inv * gg[n] + bwv[n];
      } else {
#pragma unroll
        for (int n = 0; n < 8; ++n) outb[r * 128 + n * 16 + rlo] = f2bf(v[n] * inv * gg[n] + bwv[n]);
      }
    }
  }
}

extern "C" void kernel_launch(void* const* d_in, const int* in_sizes, int n_in,
                              void* d_out, int out_size, void* d_ws, size_t ws_size,
                              hipStream_t stream) {
  (void)n_in; (void)out_size; (void)ws_size;
  const float* x = (const float*)d_in[0];
  const int* ei[4];
  const float *ew[4], *W1[4], *b1[4], *W2[4], *b2[4];
  const float *g1, *be1, *g2, *be2;
  if (in_sizes[2] == EE) {  // setup_inputs dict order
    for (int t = 0; t < 4; ++t) {
      int base = 1 + t * 6;
      ei[t] = (const int*)d_in[base + 0];
      ew[t] = (const float*)d_in[base + 1];
      W1[t] = (const float*)d_in[base + 2];
      b1[t] = (const float*)d_in[base + 3];
      W2[t] = (const float*)d_in[base + 4];
      b2[t] = (const float*)d_in[base + 5];
    }
  } else {  // reference() argument order
    for (int t = 0; t < 4; ++t) {
      ei[t] = (const int*)d_in[1 + t];
      ew[t] = (const float*)d_in[5 + t];
      W1[t] = (const float*)d_in[9 + t * 4 + 0];
      b1[t] = (const float*)d_in[9 + t * 4 + 1];
      W2[t] = (const float*)d_in[9 + t * 4 + 2];
      b2[t] = (const float*)d_in[9 + t * 4 + 3];
    }
  }
  g1 = (const float*)d_in[25];
  be1 = (const float*)d_in[26];
  g2 = (const float*)d_in[27];
  be2 = (const float*)d_in[28];

  char* ws = (char*)d_ws;
  size_t off = 0;
  auto take = [&](size_t b) { char* p = ws + off; off = (off + b + 255) & ~(size_t)255; return p; };
  unsigned* gcounts = (unsigned*)take(512 * 4);
  unsigned* rpc     = (unsigned*)take(513 * 4);
  unsigned* cursor  = (unsigned*)take(512 * 4);
  unsigned* rp_fine = (unsigned*)take((4ull * NN + 1) * 4);
  uint2* edges      = (uint2*)take(4ull * EE * 8);
  unsigned short* Xb = (unsigned short*)take((size_t)NN * 128 * 2);
  unsigned short* Z  = (unsigned short*)take((size_t)NN * 512 * 2);
  // tmp lives in the upper 16 MiB of d_out (64 MiB total); dead before Yb/final writes land
  uint2* tmp = (uint2*)((char*)d_out + 48ull * 1024 * 1024);

  hipMemsetAsync(gcounts, 0, 512 * 4, stream);
  khc<<<1024, 256, 0, stream>>>(ei[0] + EE, ei[1] + EE, ei[2] + EE, ei[3] + EE, gcounts);
  kscan_small<<<1, 512, 0, stream>>>(gcounts, rpc, cursor, rp_fine);
  kbinA<<<512, 256, 0, stream>>>(ei[0], ei[1], ei[2], ei[3], ew[0], ew[1], ew[2], ew[3], cursor, tmp);
  kbinB<<<512, 256, 0, stream>>>(rpc, tmp, rp_fine, edges);
  kcast<<<NN * 128 / 4 / 256, 256, 0, stream>>>((const float4*)x, (ushort4*)Xb);

  // layer 1
  kagg<<<NN / 4, 256, 0, stream>>>(edges, rp_fine, Xb, Z);
  unsigned short* Yb = (unsigned short*)d_out;
  gemm_ln<<<NN / 128, 256, 0, stream>>>(Z, W1[0], W1[1], W1[2], W1[3],
                                        b1[0], b1[1], b1[2], b1[3], g1, be1, Yb, nullptr, 0);
  // layer 2
  kagg<<<NN / 4, 256, 0, stream>>>(edges, rp_fine, Yb, Z);
  gemm_ln<<<NN / 128, 256, 0, stream>>>(Z, W2[0], W2[1], W2[2], W2[3],
                                        b2[0], b2[1], b2[2], b2[3], g2, be2, nullptr, (float*)d_out, 1);
}

// Round 3
// 422.391 us; speedup vs baseline: 1.6013x; 1.1925x over previous
//
#include <hip/hip_runtime.h>

#define NN 131072
#define EE 524288

typedef short bf16x8 __attribute__((ext_vector_type(8)));
typedef float f32x4 __attribute__((ext_vector_type(4)));

__device__ __forceinline__ unsigned short f2bf(float f) {
  unsigned u = __float_as_uint(f);
  u += 0x7fffu + ((u >> 16) & 1u);   // RNE
  return (unsigned short)(u >> 16);
}
__device__ __forceinline__ float bflo(unsigned u) { return __uint_as_float(u << 16); }
__device__ __forceinline__ float bfhi(unsigned u) { return __uint_as_float(u & 0xffff0000u); }

// ---------------- coarse histogram over dst>>8 (512 buckets) ----------------
__global__ __launch_bounds__(256) void khc(const int* __restrict__ d0, const int* __restrict__ d1,
                                           const int* __restrict__ d2, const int* __restrict__ d3,
                                           unsigned* __restrict__ gc) {
  __shared__ unsigned h[512];
  for (int i = threadIdx.x; i < 512; i += 256) h[i] = 0;
  __syncthreads();
  unsigned base = blockIdx.x * 2048u + threadIdx.x;
#pragma unroll
  for (int k = 0; k < 8; ++k) {
    unsigned e = base + k * 256u;
    unsigned t = e >> 19, i = e & (EE - 1u);
    const int* dd = (t == 0) ? d0 : (t == 1) ? d1 : (t == 2) ? d2 : d3;
    atomicAdd(&h[((unsigned)dd[i]) >> 8], 1u);
  }
  __syncthreads();
  for (int i = threadIdx.x; i < 512; i += 256) atomicAdd(&gc[i], h[i]);
}

// ---------------- scan 512 coarse counts -> rpc[513], cursor init ----------------
__global__ __launch_bounds__(512) void kscan_small(const unsigned* __restrict__ gc, unsigned* __restrict__ rpc,
                                                   unsigned* __restrict__ cursor, unsigned* __restrict__ rp_fine) {
  __shared__ unsigned sh[512];
  int tid = threadIdx.x;
  unsigned x = gc[tid];
  sh[tid] = x;
  __syncthreads();
  for (int o = 1; o < 512; o <<= 1) {
    unsigned v = (tid >= o) ? sh[tid - o] : 0u;
    __syncthreads();
    sh[tid] += v;
    __syncthreads();
  }
  unsigned excl = sh[tid] - x;
  rpc[tid] = excl;
  cursor[tid] = excl;
  if (tid == 511) rpc[512] = sh[511];
  if (tid == 0) rp_fine[4u * NN] = 4u * EE;
}

// ---------------- phase A: bin edges into 512 coarse buckets ----------------
// record: word0 = src | (lowkey<<17), word1 = bits(w); lowkey = (dst&255)*4 + t
__global__ __launch_bounds__(256) void kbinA(
    const int* __restrict__ e0, const int* __restrict__ e1, const int* __restrict__ e2, const int* __restrict__ e3,
    const float* __restrict__ w0, const float* __restrict__ w1, const float* __restrict__ w2, const float* __restrict__ w3,
    unsigned* __restrict__ cursor, uint2* __restrict__ tmp) {
  __shared__ unsigned hist[512];
  __shared__ unsigned base[512];
  int tid = threadIdx.x;
  unsigned t = blockIdx.x >> 7;          // 128 chunks per type
  unsigned chunk = blockIdx.x & 127u;
  const int* ei = (t == 0) ? e0 : (t == 1) ? e1 : (t == 2) ? e2 : e3;
  const float* ew = (t == 0) ? w0 : (t == 1) ? w1 : (t == 2) ? w2 : w3;
  const int* srcp = ei;
  const int* dstp = ei + EE;
  unsigned ib = chunk * 4096u;
  for (int i = tid; i < 512; i += 256) hist[i] = 0;
  __syncthreads();
  unsigned km[16], sm[16];
  float wm[16];
#pragma unroll
  for (int k = 0; k < 16; ++k) {
    unsigned i = ib + k * 256u + tid;
    unsigned dst = (unsigned)dstp[i];
    sm[k] = (unsigned)srcp[i];
    wm[k] = ew[i];
    km[k] = (dst << 2) | t;              // key = dst*4+t; bucket = key>>10
    atomicAdd(&hist[dst >> 8], 1u);
  }
  __syncthreads();
  for (int j = tid; j < 512; j += 256) {
    unsigned c = hist[j];
    base[j] = c ? atomicAdd(&cursor[j], c) : 0u;
    hist[j] = 0u;                        // reuse as local cursor
  }
  __syncthreads();
#pragma unroll
  for (int k = 0; k < 16; ++k) {
    unsigned b = km[k] >> 10;
    unsigned l = atomicAdd(&hist[b], 1u);
    tmp[(size_t)base[b] + l] = make_uint2(sm[k] | ((km[k] & 1023u) << 17), __float_as_uint(wm[k]));
  }
}

// ---------------- phase B: per-bucket counting sort over 1024 fine keys ----------------
__global__ __launch_bounds__(256) void kbinB(const unsigned* __restrict__ rpc, const uint2* __restrict__ tmp,
                                             unsigned* __restrict__ rp_fine, uint2* __restrict__ edges) {
  __shared__ unsigned cnts[1024];
  __shared__ unsigned ps[256];
  int tid = threadIdx.x;
  unsigned b = blockIdx.x;
  unsigned s = rpc[b], e = rpc[b + 1];
  unsigned cnt = e - s;
  for (int j = tid; j < 1024; j += 256) cnts[j] = 0;
  __syncthreads();
  for (unsigned i = tid; i < cnt; i += 256) {
    unsigned lk = tmp[s + i].x >> 17;
    atomicAdd(&cnts[lk], 1u);
  }
  __syncthreads();
  unsigned c4[4], lsum = 0;
#pragma unroll
  for (int q = 0; q < 4; ++q) { c4[q] = cnts[tid * 4 + q]; lsum += c4[q]; }
  ps[tid] = lsum;
  __syncthreads();
  for (int o = 1; o < 256; o <<= 1) {
    unsigned v = (tid >= o) ? ps[tid - o] : 0u;
    __syncthreads();
    ps[tid] += v;
    __syncthreads();
  }
  unsigned excl = ps[tid] - lsum;
  __syncthreads();
#pragma unroll
  for (int q = 0; q < 4; ++q) {
    rp_fine[b * 1024u + (unsigned)tid * 4u + q] = s + excl;
    cnts[tid * 4 + q] = excl;            // lcur init
    excl += c4[q];
  }
  __syncthreads();
  for (unsigned i = tid; i < cnt; i += 256) {
    uint2 r = tmp[s + i];
    unsigned lk = r.x >> 17;
    unsigned p = atomicAdd(&cnts[lk], 1u);
    edges[(size_t)s + p] = make_uint2(r.x & 0x1ffffu, r.y);
  }
}

// ---------------- fp32 -> bf16 cast ----------------
__global__ __launch_bounds__(256) void kcast(const float4* __restrict__ x, ushort4* __restrict__ o) {
  unsigned i = blockIdx.x * 256u + threadIdx.x;
  float4 v = x[i];
  ushort4 r;
  r.x = f2bf(v.x); r.y = f2bf(v.y); r.z = f2bf(v.z); r.w = f2bf(v.w);
  o[i] = r;
}

// ---------------- aggregate (pull): Z[d][t*128+c] = sum ew*X[src][c] ----------------
// 16-lane group g handles type-g segment; 16 lanes x dwordx4 = full 256B row per gather.
// The 4 segments run in parallel across groups; 2-deep pipeline in-loop.
__global__ __launch_bounds__(256) void kagg(const uint2* __restrict__ edges, const unsigned* __restrict__ rp,
                                            const unsigned short* __restrict__ X, unsigned short* __restrict__ Z) {
  const int tid = threadIdx.x;
  const int lane = tid & 63;
  const int g = lane >> 4;
  const int cl = lane & 15;
  unsigned d = (blockIdx.x << 2) + (unsigned)(tid >> 6);
  unsigned s = rp[d * 4u + g];
  unsigned e = rp[d * 4u + g + 1];
  unsigned len = e - s;
  int m = (int)len;
  m = max(m, __shfl_xor(m, 16, 64));
  m = max(m, __shfl_xor(m, 32, 64));
  float acc[8];
#pragma unroll
  for (int k = 0; k < 8; ++k) acc[k] = 0.f;
  const unsigned short* Xr = X + (size_t)(cl * 8);
  unsigned jlast = len ? e - 1u : s;
  for (int i = 0; i < m; i += 2) {
    bool v0 = (unsigned)i < len;
    bool v1 = (unsigned)(i + 1) < len;
    unsigned j0 = v0 ? s + (unsigned)i : jlast;
    unsigned j1 = v1 ? s + (unsigned)(i + 1) : jlast;
    uint2 q0 = edges[j0];
    uint2 q1 = edges[j1];
    unsigned s0 = v0 ? q0.x : 0u;
    unsigned s1 = v1 ? q1.x : 0u;
    uint4 u0 = *(const uint4*)(Xr + (size_t)s0 * 128);
    uint4 u1 = *(const uint4*)(Xr + (size_t)s1 * 128);
    float w0 = v0 ? __uint_as_float(q0.y) : 0.f;
    float w1 = v1 ? __uint_as_float(q1.y) : 0.f;
    acc[0] = fmaf(w0, bflo(u0.x), acc[0]); acc[1] = fmaf(w0, bfhi(u0.x), acc[1]);
    acc[2] = fmaf(w0, bflo(u0.y), acc[2]); acc[3] = fmaf(w0, bfhi(u0.y), acc[3]);
    acc[4] = fmaf(w0, bflo(u0.z), acc[4]); acc[5] = fmaf(w0, bfhi(u0.z), acc[5]);
    acc[6] = fmaf(w0, bflo(u0.w), acc[6]); acc[7] = fmaf(w0, bfhi(u0.w), acc[7]);
    acc[0] = fmaf(w1, bflo(u1.x), acc[0]); acc[1] = fmaf(w1, bfhi(u1.x), acc[1]);
    acc[2] = fmaf(w1, bflo(u1.y), acc[2]); acc[3] = fmaf(w1, bfhi(u1.y), acc[3]);
    acc[4] = fmaf(w1, bflo(u1.z), acc[4]); acc[5] = fmaf(w1, bfhi(u1.z), acc[5]);
    acc[6] = fmaf(w1, bflo(u1.w), acc[6]); acc[7] = fmaf(w1, bfhi(u1.w), acc[7]);
  }
  unsigned o0 = ((unsigned)f2bf(acc[1]) << 16) | (unsigned)f2bf(acc[0]);
  unsigned o1 = ((unsigned)f2bf(acc[3]) << 16) | (unsigned)f2bf(acc[2]);
  unsigned o2 = ((unsigned)f2bf(acc[5]) << 16) | (unsigned)f2bf(acc[4]);
  unsigned o3 = ((unsigned)f2bf(acc[7]) << 16) | (unsigned)f2bf(acc[6]);
  *(uint4*)(Z + (size_t)d * 512 + (unsigned)(g * 128 + cl * 8)) = make_uint4(o0, o1, o2, o3);
}

// ---------------- GEMM [N,512]x[512,128] (bf16 MFMA) + bias + LayerNorm fused ----------------
__global__ __launch_bounds__(256) void gemm_ln(
    const unsigned short* __restrict__ Z,
    const float* __restrict__ Wa, const float* __restrict__ Wb,
    const float* __restrict__ Wc, const float* __restrict__ Wd,
    const float* __restrict__ ba, const float* __restrict__ bb_,
    const float* __restrict__ bc, const float* __restrict__ bd,
    const float* __restrict__ gw, const float* __restrict__ bw,
    unsigned short* __restrict__ outb, float* __restrict__ outf, int wf32) {
  __shared__ unsigned short sA[128 * 128];
  __shared__ unsigned short sW[128 * 128];
  const int tid = threadIdx.x;
  const int lane = tid & 63;
  const int wv = tid >> 6;
  const int rlo = lane & 15;
  const int khi = lane >> 4;
  const size_t tiler = blockIdx.x;

  f32x4 acc[2][8];
#pragma unroll
  for (int m = 0; m < 2; ++m)
#pragma unroll
    for (int n = 0; n < 8; ++n) acc[m][n] = (f32x4){0.f, 0.f, 0.f, 0.f};

  const float* Ws[4] = {Wa, Wb, Wc, Wd};
  for (int t = 0; t < 4; ++t) {
    __syncthreads();
    {  // stage W_t transposed + swizzled
      const float* W = Ws[t];
      int c = tid & 127;
      int kh = tid >> 7;
      for (int k = kh; k < 128; k += 2) {
        unsigned short b = f2bf(W[k * 128 + c]);
        *(unsigned short*)((char*)sW + c * 256 + ((2 * k) ^ ((c & 7) << 4))) = b;
      }
    }
    {  // stage A chunk
#pragma unroll
      for (int it = 0; it < 8; ++it) {
        int idx = it * 256 + tid;
        int row = idx >> 4, ch = idx & 15;
        const uint4* src = reinterpret_cast<const uint4*>(Z + ((tiler * 128 + row) * 512 + t * 128));
        uint4 v = src[ch];
        *(uint4*)((char*)sA + row * 256 + ((ch * 16) ^ ((row & 7) << 4))) = v;
      }
    }
    __syncthreads();
#pragma unroll
    for (int q = 0; q < 4; ++q) {
      int ko = q * 64 + khi * 16;
      int r0 = wv * 32 + rlo;
      bf16x8 a0 = *(const bf16x8*)((const char*)sA + r0 * 256 + (ko ^ ((r0 & 7) << 4)));
      int r1 = r0 + 16;
      bf16x8 a1 = *(const bf16x8*)((const char*)sA + r1 * 256 + (ko ^ ((r1 & 7) << 4)));
#pragma unroll
      for (int n = 0; n < 8; ++n) {
        int cc = n * 16 + rlo;
        bf16x8 bfr = *(const bf16x8*)((const char*)sW + cc * 256 + (ko ^ ((cc & 7) << 4)));
        acc[0][n] = __builtin_amdgcn_mfma_f32_16x16x32_bf16(a0, bfr, acc[0][n], 0, 0, 0);
        acc[1][n] = __builtin_amdgcn_mfma_f32_16x16x32_bf16(a1, bfr, acc[1][n], 0, 0, 0);
      }
    }
  }
  float bsum[8], gg[8], bwv[8];
#pragma unroll
  for (int n = 0; n < 8; ++n) {
    int c = n * 16 + rlo;
    bsum[n] = ba[c] + bb_[c] + bc[c] + bd[c];
    gg[n] = gw[c];
    bwv[n] = bw[c];
  }
#pragma unroll
  for (int m = 0; m < 2; ++m) {
#pragma unroll
    for (int rg = 0; rg < 4; ++rg) {
      float v[8];
      float s = 0.f;
#pragma unroll
      for (int n = 0; n < 8; ++n) {
        v[n] = acc[m][n][rg] + bsum[n];
        s += v[n];
      }
      s += __shfl_xor(s, 1, 64);
      s += __shfl_xor(s, 2, 64);
      s += __shfl_xor(s, 4, 64);
      s += __shfl_xor(s, 8, 64);
      float mu = s * (1.f / 128.f);
      float ss = 0.f;
#pragma unroll
      for (int n = 0; n < 8; ++n) {
        v[n] -= mu;
        ss += v[n] * v[n];
      }
      ss += __shfl_xor(ss, 1, 64);
      ss += __shfl_xor(ss, 2, 64);
      ss += __shfl_xor(ss, 4, 64);
      ss += __shfl_xor(ss, 8, 64);
      float inv = rsqrtf(ss * (1.f / 128.f) + 1e-5f);
      size_t r = tiler * 128 + wv * 32 + m * 16 + khi * 4 + rg;
      if (wf32) {
#pragma unroll
        for (int n = 0; n < 8; ++n) outf[r * 128 + n * 16 + rlo] = v[n] * inv * gg[n] + bwv[n];
      } else {
#pragma unroll
        for (int n = 0; n < 8; ++n) outb[r * 128 + n * 16 + rlo] = f2bf(v[n] * inv * gg[n] + bwv[n]);
      }
    }
  }
}

extern "C" void kernel_launch(void* const* d_in, const int* in_sizes, int n_in,
                              void* d_out, int out_size, void* d_ws, size_t ws_size,
                              hipStream_t stream) {
  (void)n_in; (void)out_size; (void)ws_size;
  const float* x = (const float*)d_in[0];
  const int* ei[4];
  const float *ew[4], *W1[4], *b1[4], *W2[4], *b2[4];
  const float *g1, *be1, *g2, *be2;
  if (in_sizes[2] == EE) {  // setup_inputs dict order
    for (int t = 0; t < 4; ++t) {
      int base = 1 + t * 6;
      ei[t] = (const int*)d_in[base + 0];
      ew[t] = (const float*)d_in[base + 1];
      W1[t] = (const float*)d_in[base + 2];
      b1[t] = (const float*)d_in[base + 3];
      W2[t] = (const float*)d_in[base + 4];
      b2[t] = (const float*)d_in[base + 5];
    }
  } else {  // reference() argument order
    for (int t = 0; t < 4; ++t) {
      ei[t] = (const int*)d_in[1 + t];
      ew[t] = (const float*)d_in[5 + t];
      W1[t] = (const float*)d_in[9 + t * 4 + 0];
      b1[t] = (const float*)d_in[9 + t * 4 + 1];
      W2[t] = (const float*)d_in[9 + t * 4 + 2];
      b2[t] = (const float*)d_in[9 + t * 4 + 3];
    }
  }
  g1 = (const float*)d_in[25];
  be1 = (const float*)d_in[26];
  g2 = (const float*)d_in[27];
  be2 = (const float*)d_in[28];

  char* ws = (char*)d_ws;
  size_t off = 0;
  auto take = [&](size_t b) { char* p = ws + off; off = (off + b + 255) & ~(size_t)255; return p; };
  unsigned* gcounts = (unsigned*)take(512 * 4);
  unsigned* rpc     = (unsigned*)take(513 * 4);
  unsigned* cursor  = (unsigned*)take(512 * 4);
  unsigned* rp_fine = (unsigned*)take((4ull * NN + 1) * 4);
  uint2* edges      = (uint2*)take(4ull * EE * 8);
  unsigned short* Xb = (unsigned short*)take((size_t)NN * 128 * 2);
  unsigned short* Z  = (unsigned short*)take((size_t)NN * 512 * 2);
  // tmp lives in the upper 16 MiB of d_out (64 MiB total); dead before Yb/final writes land
  uint2* tmp = (uint2*)((char*)d_out + 48ull * 1024 * 1024);

  hipMemsetAsync(gcounts, 0, 512 * 4, stream);
  khc<<<1024, 256, 0, stream>>>(ei[0] + EE, ei[1] + EE, ei[2] + EE, ei[3] + EE, gcounts);
  kscan_small<<<1, 512, 0, stream>>>(gcounts, rpc, cursor, rp_fine);
  kbinA<<<512, 256, 0, stream>>>(ei[0], ei[1], ei[2], ei[3], ew[0], ew[1], ew[2], ew[3], cursor, tmp);
  kbinB<<<512, 256, 0, stream>>>(rpc, tmp, rp_fine, edges);
  kcast<<<NN * 128 / 4 / 256, 256, 0, stream>>>((const float4*)x, (ushort4*)Xb);

  // layer 1
  kagg<<<NN / 4, 256, 0, stream>>>(edges, rp_fine, Xb, Z);
  unsigned short* Yb = (unsigned short*)d_out;
  gemm_ln<<<NN / 128, 256, 0, stream>>>(Z, W1[0], W1[1], W1[2], W1[3],
                                        b1[0], b1[1], b1[2], b1[3], g1, be1, Yb, nullptr, 0);
  // layer 2
  kagg<<<NN / 4, 256, 0, stream>>>(edges, rp_fine, Yb, Z);
  gemm_ln<<<NN / 128, 256, 0, stream>>>(Z, W2[0], W2[1], W2[2], W2[3],
                                        b2[0], b2[1], b2[2], b2[3], g2, be2, nullptr, (float*)d_out, 1);
}

// Round 4
// 367.092 us; speedup vs baseline: 1.8425x; 1.1506x over previous
//
#include <hip/hip_runtime.h>

#define NN 131072
#define EE 524288

typedef short bf16x8 __attribute__((ext_vector_type(8)));
typedef float f32x4 __attribute__((ext_vector_type(4)));

__device__ __forceinline__ unsigned short f2bf(float f) {
  unsigned u = __float_as_uint(f);
  u += 0x7fffu + ((u >> 16) & 1u);   // RNE
  return (unsigned short)(u >> 16);
}
__device__ __forceinline__ float bflo(unsigned u) { return __uint_as_float(u << 16); }
__device__ __forceinline__ float bfhi(unsigned u) { return __uint_as_float(u & 0xffff0000u); }

// ---------------- coarse histogram over dst>>8 (512 buckets) ----------------
__global__ __launch_bounds__(256) void khc(const int* __restrict__ d0, const int* __restrict__ d1,
                                           const int* __restrict__ d2, const int* __restrict__ d3,
                                           unsigned* __restrict__ gc) {
  __shared__ unsigned h[512];
  for (int i = threadIdx.x; i < 512; i += 256) h[i] = 0;
  __syncthreads();
  unsigned base = blockIdx.x * 2048u + threadIdx.x;
#pragma unroll
  for (int k = 0; k < 8; ++k) {
    unsigned e = base + k * 256u;
    unsigned t = e >> 19, i = e & (EE - 1u);
    const int* dd = (t == 0) ? d0 : (t == 1) ? d1 : (t == 2) ? d2 : d3;
    atomicAdd(&h[((unsigned)dd[i]) >> 8], 1u);
  }
  __syncthreads();
  for (int i = threadIdx.x; i < 512; i += 256) atomicAdd(&gc[i], h[i]);
}

// ---------------- scan 512 coarse counts -> rpc[513], cursor init ----------------
__global__ __launch_bounds__(512) void kscan_small(const unsigned* __restrict__ gc, unsigned* __restrict__ rpc,
                                                   unsigned* __restrict__ cursor, unsigned* __restrict__ rp_fine) {
  __shared__ unsigned sh[512];
  int tid = threadIdx.x;
  unsigned x = gc[tid];
  sh[tid] = x;
  __syncthreads();
  for (int o = 1; o < 512; o <<= 1) {
    unsigned v = (tid >= o) ? sh[tid - o] : 0u;
    __syncthreads();
    sh[tid] += v;
    __syncthreads();
  }
  unsigned excl = sh[tid] - x;
  rpc[tid] = excl;
  cursor[tid] = excl;
  if (tid == 511) rpc[512] = sh[511];
  if (tid == 0) rp_fine[4u * NN] = 4u * EE;
}

// ---------------- phase A: bin edges into 512 coarse buckets ----------------
__global__ __launch_bounds__(256) void kbinA(
    const int* __restrict__ e0, const int* __restrict__ e1, const int* __restrict__ e2, const int* __restrict__ e3,
    const float* __restrict__ w0, const float* __restrict__ w1, const float* __restrict__ w2, const float* __restrict__ w3,
    unsigned* __restrict__ cursor, uint2* __restrict__ tmp) {
  __shared__ unsigned hist[512];
  __shared__ unsigned base[512];
  int tid = threadIdx.x;
  unsigned t = blockIdx.x >> 7;
  unsigned chunk = blockIdx.x & 127u;
  const int* ei = (t == 0) ? e0 : (t == 1) ? e1 : (t == 2) ? e2 : e3;
  const float* ew = (t == 0) ? w0 : (t == 1) ? w1 : (t == 2) ? w2 : w3;
  const int* srcp = ei;
  const int* dstp = ei + EE;
  unsigned ib = chunk * 4096u;
  for (int i = tid; i < 512; i += 256) hist[i] = 0;
  __syncthreads();
  unsigned km[16], sm[16];
  float wm[16];
#pragma unroll
  for (int k = 0; k < 16; ++k) {
    unsigned i = ib + k * 256u + tid;
    unsigned dst = (unsigned)dstp[i];
    sm[k] = (unsigned)srcp[i];
    wm[k] = ew[i];
    km[k] = (dst << 2) | t;
    atomicAdd(&hist[dst >> 8], 1u);
  }
  __syncthreads();
  for (int j = tid; j < 512; j += 256) {
    unsigned c = hist[j];
    base[j] = c ? atomicAdd(&cursor[j], c) : 0u;
    hist[j] = 0u;
  }
  __syncthreads();
#pragma unroll
  for (int k = 0; k < 16; ++k) {
    unsigned b = km[k] >> 10;
    unsigned l = atomicAdd(&hist[b], 1u);
    tmp[(size_t)base[b] + l] = make_uint2(sm[k] | ((km[k] & 1023u) << 17), __float_as_uint(wm[k]));
  }
}

// ---------------- phase B: per-bucket counting sort over 1024 fine keys ----------------
__global__ __launch_bounds__(256) void kbinB(const unsigned* __restrict__ rpc, const uint2* __restrict__ tmp,
                                             unsigned* __restrict__ rp_fine, uint2* __restrict__ edges) {
  __shared__ unsigned cnts[1024];
  __shared__ unsigned ps[256];
  int tid = threadIdx.x;
  unsigned b = blockIdx.x;
  unsigned s = rpc[b], e = rpc[b + 1];
  unsigned cnt = e - s;
  for (int j = tid; j < 1024; j += 256) cnts[j] = 0;
  __syncthreads();
  for (unsigned i = tid; i < cnt; i += 256) {
    unsigned lk = tmp[s + i].x >> 17;
    atomicAdd(&cnts[lk], 1u);
  }
  __syncthreads();
  unsigned c4[4], lsum = 0;
#pragma unroll
  for (int q = 0; q < 4; ++q) { c4[q] = cnts[tid * 4 + q]; lsum += c4[q]; }
  ps[tid] = lsum;
  __syncthreads();
  for (int o = 1; o < 256; o <<= 1) {
    unsigned v = (tid >= o) ? ps[tid - o] : 0u;
    __syncthreads();
    ps[tid] += v;
    __syncthreads();
  }
  unsigned excl = ps[tid] - lsum;
  __syncthreads();
#pragma unroll
  for (int q = 0; q < 4; ++q) {
    rp_fine[b * 1024u + (unsigned)tid * 4u + q] = s + excl;
    cnts[tid * 4 + q] = excl;
    excl += c4[q];
  }
  __syncthreads();
  for (unsigned i = tid; i < cnt; i += 256) {
    uint2 r = tmp[s + i];
    unsigned lk = r.x >> 17;
    unsigned p = atomicAdd(&cnts[lk], 1u);
    edges[(size_t)s + p] = make_uint2(r.x & 0x1ffffu, r.y);
  }
}

// ---------------- fp32 -> bf16 cast (X) ----------------
__global__ __launch_bounds__(256) void kcast(const float4* __restrict__ x, ushort4* __restrict__ o) {
  unsigned i = blockIdx.x * 256u + threadIdx.x;
  float4 v = x[i];
  ushort4 r;
  r.x = f2bf(v.x); r.y = f2bf(v.y); r.z = f2bf(v.z); r.w = f2bf(v.w);
  o[i] = r;
}

// ---------------- W -> pre-swizzled bf16 LDS image (8 matrices) ----------------
// img[mat][c*128 + (k ^ ((c&7)<<3))] = bf16(W[mat][k*128+c])
__global__ __launch_bounds__(256) void kwconv(
    const float* __restrict__ m0, const float* __restrict__ m1, const float* __restrict__ m2, const float* __restrict__ m3,
    const float* __restrict__ m4, const float* __restrict__ m5, const float* __restrict__ m6, const float* __restrict__ m7,
    unsigned short* __restrict__ img) {
  unsigned g = blockIdx.x * 256u + threadIdx.x;      // 0 .. 8*16384-1
  unsigned mat = g >> 14;
  unsigned r = g & 16383u;
  unsigned k = r >> 7, c = r & 127u;
  const float* W = (mat == 0) ? m0 : (mat == 1) ? m1 : (mat == 2) ? m2 : (mat == 3) ? m3
                 : (mat == 4) ? m4 : (mat == 5) ? m5 : (mat == 6) ? m6 : m7;
  img[(size_t)mat * 16384 + c * 128 + (k ^ ((c & 7u) << 3))] = f2bf(W[k * 128 + c]);
}

// ---------------- aggregate (pull), 4-deep pipeline ----------------
__global__ __launch_bounds__(256) void kagg(const uint2* __restrict__ edges, const unsigned* __restrict__ rp,
                                            const unsigned short* __restrict__ X, unsigned short* __restrict__ Z) {
  const int tid = threadIdx.x;
  const int lane = tid & 63;
  const int g = lane >> 4;
  const int cl = lane & 15;
  unsigned d = (blockIdx.x << 2) + (unsigned)(tid >> 6);
  unsigned s = rp[d * 4u + g];
  unsigned e = rp[d * 4u + g + 1];
  unsigned len = e - s;
  int m = (int)len;
  m = max(m, __shfl_xor(m, 16, 64));
  m = max(m, __shfl_xor(m, 32, 64));
  float accA[8], accB[8];
#pragma unroll
  for (int k = 0; k < 8; ++k) { accA[k] = 0.f; accB[k] = 0.f; }
  const unsigned short* Xr = X + (size_t)(cl * 8);
  unsigned jlast = len ? e - 1u : s;
  for (int i = 0; i < m; i += 4) {
    unsigned j[4], sidx[4];
    float w[4];
    uint2 q[4];
#pragma unroll
    for (int k = 0; k < 4; ++k) {
      bool v = (unsigned)(i + k) < len;
      j[k] = v ? s + (unsigned)(i + k) : jlast;
    }
#pragma unroll
    for (int k = 0; k < 4; ++k) q[k] = edges[j[k]];
#pragma unroll
    for (int k = 0; k < 4; ++k) {
      bool v = (unsigned)(i + k) < len;
      sidx[k] = v ? q[k].x : 0u;
      w[k] = v ? __uint_as_float(q[k].y) : 0.f;
    }
    uint4 u0 = *(const uint4*)(Xr + (size_t)sidx[0] * 128);
    uint4 u1 = *(const uint4*)(Xr + (size_t)sidx[1] * 128);
    uint4 u2 = *(const uint4*)(Xr + (size_t)sidx[2] * 128);
    uint4 u3 = *(const uint4*)(Xr + (size_t)sidx[3] * 128);
    accA[0] = fmaf(w[0], bflo(u0.x), accA[0]); accA[1] = fmaf(w[0], bfhi(u0.x), accA[1]);
    accA[2] = fmaf(w[0], bflo(u0.y), accA[2]); accA[3] = fmaf(w[0], bfhi(u0.y), accA[3]);
    accA[4] = fmaf(w[0], bflo(u0.z), accA[4]); accA[5] = fmaf(w[0], bfhi(u0.z), accA[5]);
    accA[6] = fmaf(w[0], bflo(u0.w), accA[6]); accA[7] = fmaf(w[0], bfhi(u0.w), accA[7]);
    accB[0] = fmaf(w[1], bflo(u1.x), accB[0]); accB[1] = fmaf(w[1], bfhi(u1.x), accB[1]);
    accB[2] = fmaf(w[1], bflo(u1.y), accB[2]); accB[3] = fmaf(w[1], bfhi(u1.y), accB[3]);
    accB[4] = fmaf(w[1], bflo(u1.z), accB[4]); accB[5] = fmaf(w[1], bfhi(u1.z), accB[5]);
    accB[6] = fmaf(w[1], bflo(u1.w), accB[6]); accB[7] = fmaf(w[1], bfhi(u1.w), accB[7]);
    accA[0] = fmaf(w[2], bflo(u2.x), accA[0]); accA[1] = fmaf(w[2], bfhi(u2.x), accA[1]);
    accA[2] = fmaf(w[2], bflo(u2.y), accA[2]); accA[3] = fmaf(w[2], bfhi(u2.y), accA[3]);
    accA[4] = fmaf(w[2], bflo(u2.z), accA[4]); accA[5] = fmaf(w[2], bfhi(u2.z), accA[5]);
    accA[6] = fmaf(w[2], bflo(u2.w), accA[6]); accA[7] = fmaf(w[2], bfhi(u2.w), accA[7]);
    accB[0] = fmaf(w[3], bflo(u3.x), accB[0]); accB[1] = fmaf(w[3], bfhi(u3.x), accB[1]);
    accB[2] = fmaf(w[3], bflo(u3.y), accB[2]); accB[3] = fmaf(w[3], bfhi(u3.y), accB[3]);
    accB[4] = fmaf(w[3], bflo(u3.z), accB[4]); accB[5] = fmaf(w[3], bfhi(u3.z), accB[5]);
    accB[6] = fmaf(w[3], bflo(u3.w), accB[6]); accB[7] = fmaf(w[3], bfhi(u3.w), accB[7]);
  }
#pragma unroll
  for (int k = 0; k < 8; ++k) accA[k] += accB[k];
  unsigned o0 = ((unsigned)f2bf(accA[1]) << 16) | (unsigned)f2bf(accA[0]);
  unsigned o1 = ((unsigned)f2bf(accA[3]) << 16) | (unsigned)f2bf(accA[2]);
  unsigned o2 = ((unsigned)f2bf(accA[5]) << 16) | (unsigned)f2bf(accA[4]);
  unsigned o3 = ((unsigned)f2bf(accA[7]) << 16) | (unsigned)f2bf(accA[6]);
  *(uint4*)(Z + (size_t)d * 512 + (unsigned)(g * 128 + cl * 8)) = make_uint4(o0, o1, o2, o3);
}

// ---------------- GEMM [N,512]x[512,128] (bf16 MFMA) + bias + LayerNorm fused ----------------
__global__ __launch_bounds__(256) void gemm_ln(
    const unsigned short* __restrict__ Z,
    const unsigned short* __restrict__ Wimg, int layer,
    const float* __restrict__ ba, const float* __restrict__ bb_,
    const float* __restrict__ bc, const float* __restrict__ bd,
    const float* __restrict__ gw, const float* __restrict__ bw,
    unsigned short* __restrict__ outb, float* __restrict__ outf, int wf32) {
  __shared__ unsigned short sA[128 * 128];
  __shared__ unsigned short sW[128 * 128];
  const int tid = threadIdx.x;
  const int lane = tid & 63;
  const int wv = tid >> 6;
  const int rlo = lane & 15;
  const int khi = lane >> 4;
  const size_t tiler = blockIdx.x;

  f32x4 acc[2][8];
#pragma unroll
  for (int m = 0; m < 2; ++m)
#pragma unroll
    for (int n = 0; n < 8; ++n) acc[m][n] = (f32x4){0.f, 0.f, 0.f, 0.f};

  for (int t = 0; t < 4; ++t) {
    __syncthreads();
    {  // stage W_t (pre-swizzled bf16 image): 32 KB identity copy
      const uint4* Wt = (const uint4*)(Wimg + (((size_t)layer * 4 + t) << 14));
#pragma unroll
      for (int i = 0; i < 8; ++i) {
        int slot = i * 256 + tid;
        ((uint4*)sW)[slot] = Wt[slot];
      }
    }
    {  // stage A chunk
#pragma unroll
      for (int it = 0; it < 8; ++it) {
        int idx = it * 256 + tid;
        int row = idx >> 4, ch = idx & 15;
        const uint4* src = reinterpret_cast<const uint4*>(Z + ((tiler * 128 + row) * 512 + t * 128));
        uint4 v = src[ch];
        *(uint4*)((char*)sA + row * 256 + ((ch * 16) ^ ((row & 7) << 4))) = v;
      }
    }
    __syncthreads();
#pragma unroll
    for (int q = 0; q < 4; ++q) {
      int ko = q * 64 + khi * 16;
      int r0 = wv * 32 + rlo;
      bf16x8 a0 = *(const bf16x8*)((const char*)sA + r0 * 256 + (ko ^ ((r0 & 7) << 4)));
      int r1 = r0 + 16;
      bf16x8 a1 = *(const bf16x8*)((const char*)sA + r1 * 256 + (ko ^ ((r1 & 7) << 4)));
#pragma unroll
      for (int n = 0; n < 8; ++n) {
        int cc = n * 16 + rlo;
        bf16x8 bfr = *(const bf16x8*)((const char*)sW + cc * 256 + (ko ^ ((cc & 7) << 4)));
        acc[0][n] = __builtin_amdgcn_mfma_f32_16x16x32_bf16(a0, bfr, acc[0][n], 0, 0, 0);
        acc[1][n] = __builtin_amdgcn_mfma_f32_16x16x32_bf16(a1, bfr, acc[1][n], 0, 0, 0);
      }
    }
  }
  float bsum[8], gg[8], bwv[8];
#pragma unroll
  for (int n = 0; n < 8; ++n) {
    int c = n * 16 + rlo;
    bsum[n] = ba[c] + bb_[c] + bc[c] + bd[c];
    gg[n] = gw[c];
    bwv[n] = bw[c];
  }
#pragma unroll
  for (int m = 0; m < 2; ++m) {
#pragma unroll
    for (int rg = 0; rg < 4; ++rg) {
      float v[8];
      float s = 0.f;
#pragma unroll
      for (int n = 0; n < 8; ++n) {
        v[n] = acc[m][n][rg] + bsum[n];
        s += v[n];
      }
      s += __shfl_xor(s, 1, 64);
      s += __shfl_xor(s, 2, 64);
      s += __shfl_xor(s, 4, 64);
      s += __shfl_xor(s, 8, 64);
      float mu = s * (1.f / 128.f);
      float ss = 0.f;
#pragma unroll
      for (int n = 0; n < 8; ++n) {
        v[n] -= mu;
        ss += v[n] * v[n];
      }
      ss += __shfl_xor(ss, 1, 64);
      ss += __shfl_xor(ss, 2, 64);
      ss += __shfl_xor(ss, 4, 64);
      ss += __shfl_xor(ss, 8, 64);
      float inv = rsqrtf(ss * (1.f / 128.f) + 1e-5f);
      size_t r = tiler * 128 + wv * 32 + m * 16 + khi * 4 + rg;
      if (wf32) {
#pragma unroll
        for (int n = 0; n < 8; ++n) outf[r * 128 + n * 16 + rlo] = v[n] * inv * gg[n] + bwv[n];
      } else {
#pragma unroll
        for (int n = 0; n < 8; ++n) outb[r * 128 + n * 16 + rlo] = f2bf(v[n] * inv * gg[n] + bwv[n]);
      }
    }
  }
}

extern "C" void kernel_launch(void* const* d_in, const int* in_sizes, int n_in,
                              void* d_out, int out_size, void* d_ws, size_t ws_size,
                              hipStream_t stream) {
  (void)n_in; (void)out_size; (void)ws_size;
  const float* x = (const float*)d_in[0];
  const int* ei[4];
  const float *ew[4], *W1[4], *b1[4], *W2[4], *b2[4];
  const float *g1, *be1, *g2, *be2;
  if (in_sizes[2] == EE) {  // setup_inputs dict order
    for (int t = 0; t < 4; ++t) {
      int base = 1 + t * 6;
      ei[t] = (const int*)d_in[base + 0];
      ew[t] = (const float*)d_in[base + 1];
      W1[t] = (const float*)d_in[base + 2];
      b1[t] = (const float*)d_in[base + 3];
      W2[t] = (const float*)d_in[base + 4];
      b2[t] = (const float*)d_in[base + 5];
    }
  } else {  // reference() argument order
    for (int t = 0; t < 4; ++t) {
      ei[t] = (const int*)d_in[1 + t];
      ew[t] = (const float*)d_in[5 + t];
      W1[t] = (const float*)d_in[9 + t * 4 + 0];
      b1[t] = (const float*)d_in[9 + t * 4 + 1];
      W2[t] = (const float*)d_in[9 + t * 4 + 2];
      b2[t] = (const float*)d_in[9 + t * 4 + 3];
    }
  }
  g1 = (const float*)d_in[25];
  be1 = (const float*)d_in[26];
  g2 = (const float*)d_in[27];
  be2 = (const float*)d_in[28];

  char* ws = (char*)d_ws;
  size_t off = 0;
  auto take = [&](size_t b) { char* p = ws + off; off = (off + b + 255) & ~(size_t)255; return p; };
  unsigned* gcounts = (unsigned*)take(512 * 4);
  unsigned* rpc     = (unsigned*)take(513 * 4);
  unsigned* cursor  = (unsigned*)take(512 * 4);
  unsigned* rp_fine = (unsigned*)take((4ull * NN + 1) * 4);
  unsigned short* Wimg = (unsigned short*)take(8ull * 16384 * 2);
  uint2* edges      = (uint2*)take(4ull * EE * 8);
  unsigned short* Xb = (unsigned short*)take((size_t)NN * 128 * 2);
  unsigned short* Z  = (unsigned short*)take((size_t)NN * 512 * 2);
  uint2* tmp = (uint2*)((char*)d_out + 48ull * 1024 * 1024);

  hipMemsetAsync(gcounts, 0, 512 * 4, stream);
  khc<<<1024, 256, 0, stream>>>(ei[0] + EE, ei[1] + EE, ei[2] + EE, ei[3] + EE, gcounts);
  kscan_small<<<1, 512, 0, stream>>>(gcounts, rpc, cursor, rp_fine);
  kbinA<<<512, 256, 0, stream>>>(ei[0], ei[1], ei[2], ei[3], ew[0], ew[1], ew[2], ew[3], cursor, tmp);
  kbinB<<<512, 256, 0, stream>>>(rpc, tmp, rp_fine, edges);
  kcast<<<NN * 128 / 4 / 256, 256, 0, stream>>>((const float4*)x, (ushort4*)Xb);
  kwconv<<<512, 256, 0, stream>>>(W1[0], W1[1], W1[2], W1[3], W2[0], W2[1], W2[2], W2[3], Wimg);

  // layer 1
  kagg<<<NN / 4, 256, 0, stream>>>(edges, rp_fine, Xb, Z);
  unsigned short* Yb = (unsigned short*)d_out;
  gemm_ln<<<NN / 128, 256, 0, stream>>>(Z, Wimg, 0, b1[0], b1[1], b1[2], b1[3], g1, be1, Yb, nullptr, 0);
  // layer 2
  kagg<<<NN / 4, 256, 0, stream>>>(edges, rp_fine, Yb, Z);
  gemm_ln<<<NN / 128, 256, 0, stream>>>(Z, Wimg, 1, b2[0], b2[1], b2[2], b2[3], g2, be2, nullptr, (float*)d_out, 1);
}

// Round 5
// 366.119 us; speedup vs baseline: 1.8474x; 1.0027x over previous
//
#include <hip/hip_runtime.h>
#include <hip/hip_fp16.h>

#define NN 131072
#define EE 524288

typedef _Float16 f16x8 __attribute__((ext_vector_type(8)));
typedef float f32x4 __attribute__((ext_vector_type(4)));

__device__ __forceinline__ unsigned short f2h(float f) {
  __half h = __float2half(f);
  unsigned short r;
  __builtin_memcpy(&r, &h, 2);
  return r;
}
__device__ __forceinline__ __half2 u2h2(unsigned u) {
  __half2 h;
  __builtin_memcpy(&h, &u, 4);
  return h;
}
__device__ __forceinline__ unsigned h22u(__half2 h) {
  unsigned u;
  __builtin_memcpy(&u, &h, 4);
  return u;
}

// ---------------- coarse histogram over dst>>8 (512 buckets) ----------------
__global__ __launch_bounds__(256) void khc(const int* __restrict__ d0, const int* __restrict__ d1,
                                           const int* __restrict__ d2, const int* __restrict__ d3,
                                           unsigned* __restrict__ gc) {
  __shared__ unsigned h[512];
  for (int i = threadIdx.x; i < 512; i += 256) h[i] = 0;
  __syncthreads();
  unsigned base = blockIdx.x * 2048u + threadIdx.x;
#pragma unroll
  for (int k = 0; k < 8; ++k) {
    unsigned e = base + k * 256u;
    unsigned t = e >> 19, i = e & (EE - 1u);
    const int* dd = (t == 0) ? d0 : (t == 1) ? d1 : (t == 2) ? d2 : d3;
    atomicAdd(&h[((unsigned)dd[i]) >> 8], 1u);
  }
  __syncthreads();
  for (int i = threadIdx.x; i < 512; i += 256) atomicAdd(&gc[i], h[i]);
}

// ---------------- scan 512 coarse counts -> rpc[513], cursor init ----------------
__global__ __launch_bounds__(512) void kscan_small(const unsigned* __restrict__ gc, unsigned* __restrict__ rpc,
                                                   unsigned* __restrict__ cursor, unsigned* __restrict__ rp_fine) {
  __shared__ unsigned sh[512];
  int tid = threadIdx.x;
  unsigned x = gc[tid];
  sh[tid] = x;
  __syncthreads();
  for (int o = 1; o < 512; o <<= 1) {
    unsigned v = (tid >= o) ? sh[tid - o] : 0u;
    __syncthreads();
    sh[tid] += v;
    __syncthreads();
  }
  unsigned excl = sh[tid] - x;
  rpc[tid] = excl;
  cursor[tid] = excl;
  if (tid == 511) rpc[512] = sh[511];
  if (tid == 0) rp_fine[4u * NN] = 4u * EE;
}

// ---------------- phase A: bin edges into 512 coarse buckets ----------------
__global__ __launch_bounds__(256) void kbinA(
    const int* __restrict__ e0, const int* __restrict__ e1, const int* __restrict__ e2, const int* __restrict__ e3,
    const float* __restrict__ w0, const float* __restrict__ w1, const float* __restrict__ w2, const float* __restrict__ w3,
    unsigned* __restrict__ cursor, uint2* __restrict__ tmp) {
  __shared__ unsigned hist[512];
  __shared__ unsigned base[512];
  int tid = threadIdx.x;
  unsigned t = blockIdx.x >> 7;
  unsigned chunk = blockIdx.x & 127u;
  const int* ei = (t == 0) ? e0 : (t == 1) ? e1 : (t == 2) ? e2 : e3;
  const float* ew = (t == 0) ? w0 : (t == 1) ? w1 : (t == 2) ? w2 : w3;
  const int* srcp = ei;
  const int* dstp = ei + EE;
  unsigned ib = chunk * 4096u;
  for (int i = tid; i < 512; i += 256) hist[i] = 0;
  __syncthreads();
  unsigned km[16], sm[16];
  float wm[16];
#pragma unroll
  for (int k = 0; k < 16; ++k) {
    unsigned i = ib + k * 256u + tid;
    unsigned dst = (unsigned)dstp[i];
    sm[k] = (unsigned)srcp[i];
    wm[k] = ew[i];
    km[k] = (dst << 2) | t;
    atomicAdd(&hist[dst >> 8], 1u);
  }
  __syncthreads();
  for (int j = tid; j < 512; j += 256) {
    unsigned c = hist[j];
    base[j] = c ? atomicAdd(&cursor[j], c) : 0u;
    hist[j] = 0u;
  }
  __syncthreads();
#pragma unroll
  for (int k = 0; k < 16; ++k) {
    unsigned b = km[k] >> 10;
    unsigned l = atomicAdd(&hist[b], 1u);
    tmp[(size_t)base[b] + l] = make_uint2(sm[k] | ((km[k] & 1023u) << 17), __float_as_uint(wm[k]));
  }
}

// ---------------- phase B: per-bucket counting sort over 1024 fine keys ----------------
__global__ __launch_bounds__(256) void kbinB(const unsigned* __restrict__ rpc, const uint2* __restrict__ tmp,
                                             unsigned* __restrict__ rp_fine, uint2* __restrict__ edges) {
  __shared__ unsigned cnts[1024];
  __shared__ unsigned ps[256];
  int tid = threadIdx.x;
  unsigned b = blockIdx.x;
  unsigned s = rpc[b], e = rpc[b + 1];
  unsigned cnt = e - s;
  for (int j = tid; j < 1024; j += 256) cnts[j] = 0;
  __syncthreads();
  for (unsigned i = tid; i < cnt; i += 256) {
    unsigned lk = tmp[s + i].x >> 17;
    atomicAdd(&cnts[lk], 1u);
  }
  __syncthreads();
  unsigned c4[4], lsum = 0;
#pragma unroll
  for (int q = 0; q < 4; ++q) { c4[q] = cnts[tid * 4 + q]; lsum += c4[q]; }
  ps[tid] = lsum;
  __syncthreads();
  for (int o = 1; o < 256; o <<= 1) {
    unsigned v = (tid >= o) ? ps[tid - o] : 0u;
    __syncthreads();
    ps[tid] += v;
    __syncthreads();
  }
  unsigned excl = ps[tid] - lsum;
  __syncthreads();
#pragma unroll
  for (int q = 0; q < 4; ++q) {
    rp_fine[b * 1024u + (unsigned)tid * 4u + q] = s + excl;
    cnts[tid * 4 + q] = excl;
    excl += c4[q];
  }
  __syncthreads();
  for (unsigned i = tid; i < cnt; i += 256) {
    uint2 r = tmp[s + i];
    unsigned lk = r.x >> 17;
    unsigned p = atomicAdd(&cnts[lk], 1u);
    edges[(size_t)s + p] = make_uint2(r.x & 0x1ffffu, r.y);
  }
}

// ---------------- fp32 -> fp16 cast (X) ----------------
__global__ __launch_bounds__(256) void kcast(const float4* __restrict__ x, ushort4* __restrict__ o) {
  unsigned i = blockIdx.x * 256u + threadIdx.x;
  float4 v = x[i];
  ushort4 r;
  r.x = f2h(v.x); r.y = f2h(v.y); r.z = f2h(v.z); r.w = f2h(v.w);
  o[i] = r;
}

// ---------------- W -> pre-swizzled fp16 image (8 matrices) ----------------
__global__ __launch_bounds__(256) void kwconv(
    const float* __restrict__ m0, const float* __restrict__ m1, const float* __restrict__ m2, const float* __restrict__ m3,
    const float* __restrict__ m4, const float* __restrict__ m5, const float* __restrict__ m6, const float* __restrict__ m7,
    unsigned short* __restrict__ img) {
  unsigned g = blockIdx.x * 256u + threadIdx.x;
  unsigned mat = g >> 14;
  unsigned r = g & 16383u;
  unsigned k = r >> 7, c = r & 127u;
  const float* W = (mat == 0) ? m0 : (mat == 1) ? m1 : (mat == 2) ? m2 : (mat == 3) ? m3
                 : (mat == 4) ? m4 : (mat == 5) ? m5 : (mat == 6) ? m6 : m7;
  img[(size_t)mat * 16384 + c * 128 + (k ^ ((c & 7u) << 3))] = f2h(W[k * 128 + c]);
}

// ---------------- aggregate (pull), fp16 packed fma, 4-deep pipeline ----------------
__global__ __launch_bounds__(512) void kagg(const uint2* __restrict__ edges, const unsigned* __restrict__ rp,
                                            const unsigned short* __restrict__ X, unsigned short* __restrict__ Z) {
  const int tid = threadIdx.x;
  const int lane = tid & 63;
  const int g = lane >> 4;
  const int cl = lane & 15;
  unsigned d = (blockIdx.x << 3) + (unsigned)(tid >> 6);
  unsigned s = rp[d * 4u + g];
  unsigned e = rp[d * 4u + g + 1];
  unsigned len = e - s;
  int m = (int)len;
  m = max(m, __shfl_xor(m, 16, 64));
  m = max(m, __shfl_xor(m, 32, 64));
  __half2 accA[4], accB[4];
  const __half2 z2 = __half2(__half(0.f), __half(0.f));
#pragma unroll
  for (int k = 0; k < 4; ++k) { accA[k] = z2; accB[k] = z2; }
  const unsigned short* Xr = X + (size_t)(cl * 8);
  unsigned jlast = len ? e - 1u : s;
  for (int i = 0; i < m; i += 4) {
    unsigned j[4], sidx[4];
    uint2 q[4];
    __half2 w2[4];
#pragma unroll
    for (int k = 0; k < 4; ++k) {
      bool v = (unsigned)(i + k) < len;
      j[k] = v ? s + (unsigned)(i + k) : jlast;
    }
#pragma unroll
    for (int k = 0; k < 4; ++k) q[k] = edges[j[k]];
#pragma unroll
    for (int k = 0; k < 4; ++k) {
      bool v = (unsigned)(i + k) < len;
      sidx[k] = v ? q[k].x : 0u;
      w2[k] = __float2half2_rn(v ? __uint_as_float(q[k].y) : 0.f);
    }
    uint4 u0 = *(const uint4*)(Xr + (size_t)sidx[0] * 128);
    uint4 u1 = *(const uint4*)(Xr + (size_t)sidx[1] * 128);
    uint4 u2 = *(const uint4*)(Xr + (size_t)sidx[2] * 128);
    uint4 u3 = *(const uint4*)(Xr + (size_t)sidx[3] * 128);
    accA[0] = __hfma2(w2[0], u2h2(u0.x), accA[0]);
    accA[1] = __hfma2(w2[0], u2h2(u0.y), accA[1]);
    accA[2] = __hfma2(w2[0], u2h2(u0.z), accA[2]);
    accA[3] = __hfma2(w2[0], u2h2(u0.w), accA[3]);
    accB[0] = __hfma2(w2[1], u2h2(u1.x), accB[0]);
    accB[1] = __hfma2(w2[1], u2h2(u1.y), accB[1]);
    accB[2] = __hfma2(w2[1], u2h2(u1.z), accB[2]);
    accB[3] = __hfma2(w2[1], u2h2(u1.w), accB[3]);
    accA[0] = __hfma2(w2[2], u2h2(u2.x), accA[0]);
    accA[1] = __hfma2(w2[2], u2h2(u2.y), accA[1]);
    accA[2] = __hfma2(w2[2], u2h2(u2.z), accA[2]);
    accA[3] = __hfma2(w2[2], u2h2(u2.w), accA[3]);
    accB[0] = __hfma2(w2[3], u2h2(u3.x), accB[0]);
    accB[1] = __hfma2(w2[3], u2h2(u3.y), accB[1]);
    accB[2] = __hfma2(w2[3], u2h2(u3.z), accB[2]);
    accB[3] = __hfma2(w2[3], u2h2(u3.w), accB[3]);
  }
  uint4 o;
  o.x = h22u(__hadd2(accA[0], accB[0]));
  o.y = h22u(__hadd2(accA[1], accB[1]));
  o.z = h22u(__hadd2(accA[2], accB[2]));
  o.w = h22u(__hadd2(accA[3], accB[3]));
  *(uint4*)(Z + (size_t)d * 512 + (unsigned)(g * 128 + cl * 8)) = o;
}

// ---------------- GEMM [N,512]x[512,128] (fp16 MFMA) + bias + LayerNorm fused ----------------
__global__ __launch_bounds__(256) void gemm_ln(
    const unsigned short* __restrict__ Z,
    const unsigned short* __restrict__ Wimg, int layer,
    const float* __restrict__ ba, const float* __restrict__ bb_,
    const float* __restrict__ bc, const float* __restrict__ bd,
    const float* __restrict__ gw, const float* __restrict__ bw,
    unsigned short* __restrict__ outh, float* __restrict__ outf, int wf32) {
  __shared__ unsigned short sA[128 * 128];
  __shared__ unsigned short sW[128 * 128];
  const int tid = threadIdx.x;
  const int lane = tid & 63;
  const int wv = tid >> 6;
  const int rlo = lane & 15;
  const int khi = lane >> 4;
  const size_t tiler = blockIdx.x;

  f32x4 acc[2][8];
#pragma unroll
  for (int m = 0; m < 2; ++m)
#pragma unroll
    for (int n = 0; n < 8; ++n) acc[m][n] = (f32x4){0.f, 0.f, 0.f, 0.f};

  for (int t = 0; t < 4; ++t) {
    __syncthreads();
    {  // stage W_t (pre-swizzled fp16 image): 32 KB identity copy
      const uint4* Wt = (const uint4*)(Wimg + (((size_t)layer * 4 + t) << 14));
#pragma unroll
      for (int i = 0; i < 8; ++i) {
        int slot = i * 256 + tid;
        ((uint4*)sW)[slot] = Wt[slot];
      }
    }
    {  // stage A chunk
#pragma unroll
      for (int it = 0; it < 8; ++it) {
        int idx = it * 256 + tid;
        int row = idx >> 4, ch = idx & 15;
        const uint4* src = reinterpret_cast<const uint4*>(Z + ((tiler * 128 + row) * 512 + t * 128));
        uint4 v = src[ch];
        *(uint4*)((char*)sA + row * 256 + ((ch * 16) ^ ((row & 7) << 4))) = v;
      }
    }
    __syncthreads();
#pragma unroll
    for (int q = 0; q < 4; ++q) {
      int ko = q * 64 + khi * 16;
      int r0 = wv * 32 + rlo;
      f16x8 a0 = *(const f16x8*)((const char*)sA + r0 * 256 + (ko ^ ((r0 & 7) << 4)));
      int r1 = r0 + 16;
      f16x8 a1 = *(const f16x8*)((const char*)sA + r1 * 256 + (ko ^ ((r1 & 7) << 4)));
#pragma unroll
      for (int n = 0; n < 8; ++n) {
        int cc = n * 16 + rlo;
        f16x8 bfr = *(const f16x8*)((const char*)sW + cc * 256 + (ko ^ ((cc & 7) << 4)));
        acc[0][n] = __builtin_amdgcn_mfma_f32_16x16x32_f16(a0, bfr, acc[0][n], 0, 0, 0);
        acc[1][n] = __builtin_amdgcn_mfma_f32_16x16x32_f16(a1, bfr, acc[1][n], 0, 0, 0);
      }
    }
  }
  float bsum[8], gg[8], bwv[8];
#pragma unroll
  for (int n = 0; n < 8; ++n) {
    int c = n * 16 + rlo;
    bsum[n] = ba[c] + bb_[c] + bc[c] + bd[c];
    gg[n] = gw[c];
    bwv[n] = bw[c];
  }
#pragma unroll
  for (int m = 0; m < 2; ++m) {
#pragma unroll
    for (int rg = 0; rg < 4; ++rg) {
      float v[8];
      float s = 0.f;
#pragma unroll
      for (int n = 0; n < 8; ++n) {
        v[n] = acc[m][n][rg] + bsum[n];
        s += v[n];
      }
      s += __shfl_xor(s, 1, 64);
      s += __shfl_xor(s, 2, 64);
      s += __shfl_xor(s, 4, 64);
      s += __shfl_xor(s, 8, 64);
      float mu = s * (1.f / 128.f);
      float ss = 0.f;
#pragma unroll
      for (int n = 0; n < 8; ++n) {
        v[n] -= mu;
        ss += v[n] * v[n];
      }
      ss += __shfl_xor(ss, 1, 64);
      ss += __shfl_xor(ss, 2, 64);
      ss += __shfl_xor(ss, 4, 64);
      ss += __shfl_xor(ss, 8, 64);
      float inv = rsqrtf(ss * (1.f / 128.f) + 1e-5f);
      size_t r = tiler * 128 + wv * 32 + m * 16 + khi * 4 + rg;
      if (wf32) {
#pragma unroll
        for (int n = 0; n < 8; ++n) outf[r * 128 + n * 16 + rlo] = v[n] * inv * gg[n] + bwv[n];
      } else {
#pragma unroll
        for (int n = 0; n < 8; ++n) outh[r * 128 + n * 16 + rlo] = f2h(v[n] * inv * gg[n] + bwv[n]);
      }
    }
  }
}

extern "C" void kernel_launch(void* const* d_in, const int* in_sizes, int n_in,
                              void* d_out, int out_size, void* d_ws, size_t ws_size,
                              hipStream_t stream) {
  (void)n_in; (void)out_size; (void)ws_size;
  const float* x = (const float*)d_in[0];
  const int* ei[4];
  const float *ew[4], *W1[4], *b1[4], *W2[4], *b2[4];
  const float *g1, *be1, *g2, *be2;
  if (in_sizes[2] == EE) {  // setup_inputs dict order
    for (int t = 0; t < 4; ++t) {
      int base = 1 + t * 6;
      ei[t] = (const int*)d_in[base + 0];
      ew[t] = (const float*)d_in[base + 1];
      W1[t] = (const float*)d_in[base + 2];
      b1[t] = (const float*)d_in[base + 3];
      W2[t] = (const float*)d_in[base + 4];
      b2[t] = (const float*)d_in[base + 5];
    }
  } else {  // reference() argument order
    for (int t = 0; t < 4; ++t) {
      ei[t] = (const int*)d_in[1 + t];
      ew[t] = (const float*)d_in[5 + t];
      W1[t] = (const float*)d_in[9 + t * 4 + 0];
      b1[t] = (const float*)d_in[9 + t * 4 + 1];
      W2[t] = (const float*)d_in[9 + t * 4 + 2];
      b2[t] = (const float*)d_in[9 + t * 4 + 3];
    }
  }
  g1 = (const float*)d_in[25];
  be1 = (const float*)d_in[26];
  g2 = (const float*)d_in[27];
  be2 = (const float*)d_in[28];

  char* ws = (char*)d_ws;
  size_t off = 0;
  auto take = [&](size_t b) { char* p = ws + off; off = (off + b + 255) & ~(size_t)255; return p; };
  unsigned* gcounts = (unsigned*)take(512 * 4);
  unsigned* rpc     = (unsigned*)take(513 * 4);
  unsigned* cursor  = (unsigned*)take(512 * 4);
  unsigned* rp_fine = (unsigned*)take((4ull * NN + 1) * 4);
  unsigned short* Wimg = (unsigned short*)take(8ull * 16384 * 2);
  uint2* edges      = (uint2*)take(4ull * EE * 8);
  unsigned short* Xh = (unsigned short*)take((size_t)NN * 128 * 2);
  unsigned short* Z  = (unsigned short*)take((size_t)NN * 512 * 2);
  uint2* tmp = (uint2*)((char*)d_out + 48ull * 1024 * 1024);

  hipMemsetAsync(gcounts, 0, 512 * 4, stream);
  khc<<<1024, 256, 0, stream>>>(ei[0] + EE, ei[1] + EE, ei[2] + EE, ei[3] + EE, gcounts);
  kscan_small<<<1, 512, 0, stream>>>(gcounts, rpc, cursor, rp_fine);
  kbinA<<<512, 256, 0, stream>>>(ei[0], ei[1], ei[2], ei[3], ew[0], ew[1], ew[2], ew[3], cursor, tmp);
  kbinB<<<512, 256, 0, stream>>>(rpc, tmp, rp_fine, edges);
  kcast<<<NN * 128 / 4 / 256, 256, 0, stream>>>((const float4*)x, (ushort4*)Xh);
  kwconv<<<512, 256, 0, stream>>>(W1[0], W1[1], W1[2], W1[3], W2[0], W2[1], W2[2], W2[3], Wimg);

  // layer 1
  kagg<<<NN / 8, 512, 0, stream>>>(edges, rp_fine, Xh, Z);
  unsigned short* Yh = (unsigned short*)d_out;
  gemm_ln<<<NN / 128, 256, 0, stream>>>(Z, Wimg, 0, b1[0], b1[1], b1[2], b1[3], g1, be1, Yh, nullptr, 0);
  // layer 2
  kagg<<<NN / 8, 512, 0, stream>>>(edges, rp_fine, Yh, Z);
  gemm_ln<<<NN / 128, 256, 0, stream>>>(Z, Wimg, 1, b2[0], b2[1], b2[2], b2[3], g2, be2, nullptr, (float*)d_out, 1);
}